// Round 6
// baseline (372.317 us; speedup 1.0000x reference)
//
#include <hip/hip_runtime.h>
#include <math.h>

#define kB 2
#define kS 2048
#define kD 1024
#define kH 16
#define kM (kB * kS)     /* 4096 */

typedef unsigned short u16;
typedef unsigned int u32;
typedef unsigned long long u64;
typedef short s16x8 __attribute__((ext_vector_type(8)));     /* bf16 MFMA frag */
typedef float f32x4 __attribute__((ext_vector_type(4)));     /* MFMA acc */

/* fp32 -> bf16 round-to-nearest-even (scalar) */
__device__ __forceinline__ u16 f2bf(float f) {
    u32 u = __float_as_uint(f);
    u += 0x7FFFu + ((u >> 16) & 1u);
    return (u16)(u >> 16);
}

/* pack two fp32 -> two bf16 in one u32 (round-half-up + v_perm) */
__device__ __forceinline__ u32 pack_bf2(float f0, float f1) {
    const u32 r0 = __float_as_uint(f0) + 0x8000u;
    const u32 r1 = __float_as_uint(f1) + 0x8000u;
    return __builtin_amdgcn_perm(r1, r0, 0x07060302u);  /* [bf16(f1):bf16(f0)] */
}

typedef __attribute__((address_space(1))) void as1_void;
typedef __attribute__((address_space(3))) void as3_void;
__device__ __forceinline__ void async_copy16(const void* g, void* l) {
    __builtin_amdgcn_global_load_lds((as1_void*)(unsigned long long)g,
                                     (as3_void*)(unsigned)(unsigned long long)l,
                                     16, 0, 0);
}

/* ---------------- fused prep: bf16 converts + mask bit-pack ----------------
 * blocks [0,12288): X converts (3 x 4096)
 * blocks [12288,16384): W converts (4 x 1024)
 * blocks [16384,49152): mask bit-pack, one wave per (b, q, 64-key tile t):
 *   mb[(b*32+t)*2048 + q] = ballot(mask[b][q][t*64+lane] != 0)
 *   (reads coalesced 256B per wave; attn reads 16 consecutive u64 per wave)
 */
__global__ __launch_bounds__(256) void prep(
        const float* __restrict__ xq, const float* __restrict__ xk, const float* __restrict__ xv,
        const float* __restrict__ Wq, const float* __restrict__ Wk,
        const float* __restrict__ Wv, const float* __restrict__ Wo,
        const int* __restrict__ msk,
        u16* __restrict__ xqb, u16* __restrict__ xkb, u16* __restrict__ xvb,
        u16* __restrict__ wqb, u16* __restrict__ wkb, u16* __restrict__ wvb,
        u16* __restrict__ wob, u64* __restrict__ mb) {
    const int bid = blockIdx.x;
    const int tid = threadIdx.x;
    if (bid < 16384) {
        const float* in;
        u16* out;
        int i;
        if (bid < 12288) {
            const int z = bid >> 12;
            in = z == 0 ? xq : (z == 1 ? xk : xv);
            out = z == 0 ? xqb : (z == 1 ? xkb : xvb);
            i = (bid & 4095) * 256 + tid;
        } else {
            const int z = (bid - 12288) >> 10;
            in = z == 0 ? Wq : (z == 1 ? Wk : (z == 2 ? Wv : Wo));
            out = z == 0 ? wqb : (z == 1 ? wkb : (z == 2 ? wvb : wob));
            i = ((bid - 12288) & 1023) * 256 + tid;
        }
        const float4 v = ((const float4*)in)[i];
        ushort4 o;
        o.x = f2bf(v.x); o.y = f2bf(v.y); o.z = f2bf(v.z); o.w = f2bf(v.w);
        ((ushort4*)out)[i] = o;
    } else {
        const int wid = (bid - 16384) * 4 + (tid >> 6);   /* 0..131071 */
        const int lane = tid & 63;
        const int b = wid >> 16, q = (wid >> 5) & 2047, t = wid & 31;
        const int v = msk[((size_t)b * kS + q) * kS + t * 64 + lane];
        const u64 bits = __ballot(v != 0);
        if (lane == 0) mb[((size_t)b * 32 + t) * kS + q] = bits;
    }
}

/* ---------------- bf16 GEMM: C = A[M,K] @ W[N,K]^T + bias ----------------
 * 128x128 tile, BK=64 (2 barriers per 64-k: halved drain count), 4 waves
 * (2x2 of 64x64), 16x16x32 MFMA, global_load_lds width-16, XOR-swizzled LDS
 * (rows 128B = 8 chunks; chunk c of row r at slot c^(r&7)).
 * MODE 0: bf16 out; MODE 2: f32 out; MODE 3: V^T out [(b*H+h)*64+d][s].
 */
template <int MODE>
__device__ __forceinline__ void gemm_bt_body(const u16* __restrict__ A,
                                             const u16* __restrict__ W,
                                             const float* __restrict__ bias,
                                             void* __restrict__ Cp) {
    __shared__ u16 As[128 * 64];
    __shared__ u16 Bs[128 * 64];
    const int tid = threadIdx.x;
    const int wave = tid >> 6, lane = tid & 63;
    const int l15 = lane & 15, quad = lane >> 4, l7 = lane & 7;
    const int wr = wave >> 1, wc = wave & 1;
    const int m0 = (MODE == 3 ? blockIdx.x : blockIdx.y) * 128;
    const int n0 = (MODE == 3 ? blockIdx.y : blockIdx.x) * 128;

    const int srow = lane >> 3;          /* 0..7 */
    const int schk = l7 ^ srow;          /* global chunk this lane fetches */
    const u16* gA = A + (size_t)(m0 + 32 * wave + srow) * kD + schk * 8;
    const u16* gB = W + (size_t)(n0 + 32 * wave + srow) * kD + schk * 8;
    u16* lA = As + (32 * wave) * 64;
    u16* lB = Bs + (32 * wave) * 64;

    f32x4 acc[4][4];
#pragma unroll
    for (int i = 0; i < 4; ++i)
#pragma unroll
        for (int j = 0; j < 4; ++j) acc[i][j] = (f32x4)0.f;

    for (int kt = 0; kt < kD; kt += 64) {
        __syncthreads();
#pragma unroll
        for (int i = 0; i < 4; ++i) {
            async_copy16(gA + (size_t)(8 * i) * kD + kt, lA + (8 * i) * 64);
            async_copy16(gB + (size_t)(8 * i) * kD + kt, lB + (8 * i) * 64);
        }
        __syncthreads();

#pragma unroll
        for (int s = 0; s < 2; ++s) {
            const int rdoff = ((s * 4 + quad) ^ l7) * 8;
            s16x8 af[4], bf[4];
#pragma unroll
            for (int fm = 0; fm < 4; ++fm)
                af[fm] = *(const s16x8*)(As + (wr * 64 + fm * 16 + l15) * 64 + rdoff);
#pragma unroll
            for (int fn = 0; fn < 4; ++fn)
                bf[fn] = *(const s16x8*)(Bs + (wc * 64 + fn * 16 + l15) * 64 + rdoff);
#pragma unroll
            for (int fm = 0; fm < 4; ++fm)
#pragma unroll
                for (int fn = 0; fn < 4; ++fn)
                    acc[fm][fn] = __builtin_amdgcn_mfma_f32_16x16x32_bf16(
                        af[fm], bf[fn], acc[fm][fn], 0, 0, 0);
        }
    }

    /* epilogue: C/D layout col=lane&15, row=quad*4+reg */
    if constexpr (MODE == 3) {
#pragma unroll
        for (int fn = 0; fn < 4; ++fn) {
            const int sglob = n0 + wc * 64 + fn * 16 + l15;
            const int bb = sglob >> 11, ss = sglob & (kS - 1);
#pragma unroll
            for (int fm = 0; fm < 4; ++fm) {
                const int dglob = m0 + wr * 64 + fm * 16 + quad * 4;
                const float4 b4 = *(const float4*)(bias + dglob);
                const float bb4[4] = {b4.x, b4.y, b4.z, b4.w};
                const int hh = dglob >> 6, dd = dglob & 63;
                u16* base = (u16*)Cp + ((size_t)(bb * kH + hh) * 64 + dd) * kS + ss;
#pragma unroll
                for (int r = 0; r < 4; ++r)
                    base[(size_t)r * kS] = f2bf(acc[fm][fn][r] + bb4[r]);
            }
        }
    } else {
#pragma unroll
        for (int fn = 0; fn < 4; ++fn) {
            const int col = n0 + wc * 64 + fn * 16 + l15;
            const float bv = bias[col];
#pragma unroll
            for (int fm = 0; fm < 4; ++fm) {
                const int row = m0 + wr * 64 + fm * 16 + quad * 4;
#pragma unroll
                for (int r = 0; r < 4; ++r) {
                    const float v = acc[fm][fn][r] + bv;
                    if constexpr (MODE == 0)
                        ((u16*)Cp)[(size_t)(row + r) * kD + col] = f2bf(v);
                    else
                        ((float*)Cp)[(size_t)(row + r) * kD + col] = v;
                }
            }
        }
    }
}

__global__ __launch_bounds__(256) void qkv_gemm(
        const u16* __restrict__ xq, const u16* __restrict__ xk, const u16* __restrict__ xv,
        const u16* __restrict__ wq, const u16* __restrict__ wk, const u16* __restrict__ wv,
        const float* __restrict__ bq, const float* __restrict__ bk, const float* __restrict__ bv,
        u16* __restrict__ q, u16* __restrict__ k, u16* __restrict__ vt) {
    const int z = blockIdx.z;
    if (z == 0)      gemm_bt_body<0>(xq, wq, bq, q);
    else if (z == 1) gemm_bt_body<0>(xk, wk, bk, k);
    else             gemm_bt_body<3>(wv, xv, bv, vt);   /* V^T = Wv · X^T */
}

__global__ __launch_bounds__(256) void o_gemm(const u16* __restrict__ A,
                                              const u16* __restrict__ W,
                                              const float* __restrict__ bias,
                                              float* __restrict__ C) {
    gemm_bt_body<2>(A, W, bias, C);
}

/* ---------------- MFMA flash attention v4 ----------------
 * Back to 64-q blocks (1024 blocks: 4/CU residency). Wave w owns queries
 * [16w,16w+16). Scores^T = K·Q^T (lane = one query, col l15).
 * LDS only QPs (Q then P, 8K) + Ks (8K) = 16 KB.
 * V^T fragments read DIRECTLY from global (wave/q-block invariant; VMEM pipe,
 * hidden under score+softmax); mask read as u64 bit-words from global
 * (128B/wave, quad-broadcast), applied as p *= (float)bit.
 * Fixed-max softmax p=exp2(fma(s,kC,-8)); l via ones-MFMA.
 */
#define kC 0.180336880f   /* 0.125 * log2(e) */

__global__ __launch_bounds__(256) void attn_mfma(const u16* __restrict__ Qb,
                                                 const u16* __restrict__ Kb,
                                                 const u16* __restrict__ Vt,
                                                 const u64* __restrict__ mb,
                                                 u16* __restrict__ Ob) {
    __shared__ u16 QPs[64 * 64];   /* Q staged, then P (wave-private rows) */
    __shared__ u16 Ks[64 * 64];

    const int tid = threadIdx.x;
    const int wave = tid >> 6, lane = tid & 63;
    const int l15 = lane & 15, quad = lane >> 4, l7 = lane & 7;
    const int q0 = blockIdx.x * 64;
    const int b = blockIdx.y >> 4, h = blockIdx.y & 15;

    const int srow = lane >> 3;           /* 0..7 */
    const int schk = l7 ^ srow;

    /* stage Q once (natural [q][d]) */
    {
        const u16* g0 = Qb + ((size_t)(b * kS + q0 + 16 * wave + srow)) * kD + h * 64 + schk * 8;
        async_copy16(g0, QPs + (16 * wave) * 64);
        async_copy16(g0 + 8 * kD, QPs + (16 * wave + 8) * 64);
    }
    const u16* gK = Kb + ((size_t)(b * kS + 16 * wave + srow)) * kD + h * 64 + schk * 8;
    /* V^T frag base: row d = fd*16+l15, k-octet = kc*32+quad*8 */
    const u16* gVf = Vt + ((size_t)((b * kH + h) * 64 + l15)) * kS + quad * 8;
    const u64* mrow = mb + (size_t)b * 32 * kS + (q0 + 16 * wave + l15);

    f32x4 oacc[4];
#pragma unroll
    for (int i = 0; i < 4; ++i) oacc[i] = (f32x4)0.f;
    f32x4 lacc = (f32x4)0.f;

    s16x8 ones;
#pragma unroll
    for (int j = 0; j < 8; ++j) ones[j] = (short)0x3F80;   /* bf16 1.0 */

    __syncthreads();   /* Q landed */
    s16x8 qf[2];
    qf[0] = *(const s16x8*)(QPs + (16 * wave + l15) * 64 + ((0 + quad) ^ l7) * 8);
    qf[1] = *(const s16x8*)(QPs + (16 * wave + l15) * 64 + ((4 + quad) ^ l7) * 8);
    u16* psrow = QPs + (16 * wave + l15) * 64;

    for (int t = 0; t < kS / 64; ++t) {
        const int kt = t * 64;

        /* issue V^T frag loads + mask load early (VMEM; hidden under scores) */
        s16x8 av[2][4];
#pragma unroll
        for (int kc = 0; kc < 2; ++kc)
#pragma unroll
            for (int fd = 0; fd < 4; ++fd)
                av[kc][fd] = *(const s16x8*)(gVf + (size_t)(fd * 16) * kS + kt + kc * 32);
        const u64 m64 = mrow[(size_t)t * kS];
        const u32 klo = (u32)m64, khi = (u32)(m64 >> 32);

        __syncthreads();                  /* prev Ks reads done */
        async_copy16(gK + (size_t)kt * kD, Ks + (16 * wave) * 64);
        async_copy16(gK + (size_t)(kt + 8) * kD, Ks + (16 * wave + 8) * 64);
        __syncthreads();                  /* staging landed (drains av/m64 too) */

        /* scores^T: D[key][query], A=K rows, B=Q frags */
        f32x4 s[4];
#pragma unroll
        for (int fn = 0; fn < 4; ++fn) s[fn] = (f32x4)0.f;
#pragma unroll
        for (int kc = 0; kc < 2; ++kc)
#pragma unroll
            for (int fn = 0; fn < 4; ++fn) {
                const s16x8 ak = *(const s16x8*)(Ks + (fn * 16 + l15) * 64 +
                                                 ((kc * 4 + quad) ^ l7) * 8);
                s[fn] = __builtin_amdgcn_mfma_f32_16x16x32_bf16(ak, qf[kc], s[fn], 0, 0, 0);
            }

        /* fixed-max softmax + bit-mask + pack + write P (wave-private rows) */
#pragma unroll
        for (int fn = 0; fn < 4; ++fn) {
            const u32 w32 = (fn & 2) ? khi : klo;
            const u32 sh = (fn & 1) * 16 + quad * 4;
            float p[4];
#pragma unroll
            for (int r = 0; r < 4; ++r) {
                p[r] = exp2f(fmaf(s[fn][r], kC, -8.0f));
                p[r] *= (float)((w32 >> (sh + r)) & 1u);
            }
            uint2 o;
            o.x = pack_bf2(p[0], p[1]);
            o.y = pack_bf2(p[2], p[3]);
            *(uint2*)(psrow + ((fn * 2 + (quad >> 1)) ^ l7) * 8 + (quad & 1) * 4) = o;
        }

        /* PV + l: A=V^T (global regs), B=P (LDS, wave-private) */
#pragma unroll
        for (int kc = 0; kc < 2; ++kc) {
            const s16x8 bp = *(const s16x8*)(psrow + ((kc * 4 + quad) ^ l7) * 8);
            lacc = __builtin_amdgcn_mfma_f32_16x16x32_bf16(ones, bp, lacc, 0, 0, 0);
#pragma unroll
            for (int fd = 0; fd < 4; ++fd)
                oacc[fd] = __builtin_amdgcn_mfma_f32_16x16x32_bf16(
                    av[kc][fd], bp, oacc[fd], 0, 0, 0);
        }
    }

    /* epilogue: O^T[d][q] -> Ob[q][h*64+d] */
    const float inv = 1.f / lacc[0];
    const size_t orow = (size_t)(b * kS + q0 + 16 * wave + l15);
#pragma unroll
    for (int fd = 0; fd < 4; ++fd) {
        uint2 o;
        o.x = pack_bf2(oacc[fd][0] * inv, oacc[fd][1] * inv);
        o.y = pack_bf2(oacc[fd][2] * inv, oacc[fd][3] * inv);
        *(uint2*)(Ob + orow * kD + h * 64 + fd * 16 + quad * 4) = o;
    }
}

extern "C" void kernel_launch(void* const* d_in, const int* in_sizes, int n_in,
                              void* d_out, int out_size, void* d_ws, size_t ws_size,
                              hipStream_t stream) {
    const float* xq = (const float*)d_in[0];
    const float* xk = (const float*)d_in[1];
    const float* xv = (const float*)d_in[2];
    const int*  msk = (const int*)d_in[3];
    const float* Wq = (const float*)d_in[4];
    const float* bq = (const float*)d_in[5];
    const float* Wk = (const float*)d_in[6];
    const float* bk = (const float*)d_in[7];
    const float* Wv = (const float*)d_in[8];
    const float* bv = (const float*)d_in[9];
    const float* Wo = (const float*)d_in[10];
    const float* bo = (const float*)d_in[11];
    float* out = (float*)d_out;

    const size_t NX = (size_t)kM * kD;      /* 4,194,304 */
    const size_t NW = (size_t)kD * kD;      /* 1,048,576 */

    u64* mb = (u64*)d_ws;                   /* 131072 u64 = 1 MiB */
    u16* p = (u16*)((char*)d_ws + (1 << 20));
    u16* xqb = p; p += NX;
    u16* xkb = p; p += NX;
    u16* xvb = p; p += NX;
    u16* wqb = p; p += NW;
    u16* wkb = p; p += NW;
    u16* wvb = p; p += NW;
    u16* wob = p; p += NW;
    u16* qb  = p; p += NX;
    u16* kb  = p; p += NX;
    u16* vtb = p; p += NX;
    u16* ab  = xqb;                         /* reuse: xqb dead after qkv_gemm */

    prep<<<49152, 256, 0, stream>>>(xq, xk, xv, Wq, Wk, Wv, Wo, msk,
                                    xqb, xkb, xvb, wqb, wkb, wvb, wob, mb);

    dim3 gq(kD / 128, kM / 128, 3);         /* (8,32,3) = 768 blocks */
    qkv_gemm<<<gq, 256, 0, stream>>>(xqb, xkb, xvb, wqb, wkb, wvb, bq, bk, bv, qb, kb, vtb);

    dim3 ga(kS / 64, kB * kH);              /* (32,32) = 1024 blocks */
    attn_mfma<<<ga, 256, 0, stream>>>(qb, kb, vtb, mb, ab);

    dim3 go(kD / 128, kM / 128);            /* (8,32) = 256 blocks */
    o_gemm<<<go, 256, 0, stream>>>(ab, wob, bo, out);
}

// Round 7
// 280.579 us; speedup vs baseline: 1.3270x; 1.3270x over previous
//
#include <hip/hip_runtime.h>
#include <math.h>

#define kB 2
#define kS 2048
#define kD 1024
#define kH 16
#define kM (kB * kS)     /* 4096 */

typedef unsigned short u16;
typedef unsigned int u32;
typedef unsigned long long u64;
typedef short s16x8 __attribute__((ext_vector_type(8)));     /* bf16 MFMA frag */
typedef float f32x4 __attribute__((ext_vector_type(4)));     /* MFMA acc */

/* fp32 -> bf16 round-to-nearest-even (scalar) */
__device__ __forceinline__ u16 f2bf(float f) {
    u32 u = __float_as_uint(f);
    u += 0x7FFFu + ((u >> 16) & 1u);
    return (u16)(u >> 16);
}

/* pack two fp32 -> two bf16 in one u32 (round-half-up + v_perm) */
__device__ __forceinline__ u32 pack_bf2(float f0, float f1) {
    const u32 r0 = __float_as_uint(f0) + 0x8000u;
    const u32 r1 = __float_as_uint(f1) + 0x8000u;
    return __builtin_amdgcn_perm(r1, r0, 0x07060302u);  /* [bf16(f1):bf16(f0)] */
}

typedef __attribute__((address_space(1))) void as1_void;
typedef __attribute__((address_space(3))) void as3_void;
__device__ __forceinline__ void async_copy16(const void* g, void* l) {
    __builtin_amdgcn_global_load_lds((as1_void*)(unsigned long long)g,
                                     (as3_void*)(unsigned)(unsigned long long)l,
                                     16, 0, 0);
}

/* ---------------- fused prep: bf16 converts + mask permute (R4 verbatim) ----
 * blocks [0,12288): X converts (3 x 4096)
 * blocks [12288,16384): W converts (4 x 1024)
 * blocks [16384,18432): mask permute -> per-(wave-tile, element) lane masks:
 *   prepM[((b*128+qb)*32+kt)*16 + e], bit[lane] = mask[b][qb*16+(lane&15)]
 *                       [kt*64 + (lane>>4)*4 + (e>>2)*16 + (e&3)]
 */
__global__ __launch_bounds__(256) void prep(
        const float* __restrict__ xq, const float* __restrict__ xk, const float* __restrict__ xv,
        const float* __restrict__ Wq, const float* __restrict__ Wk,
        const float* __restrict__ Wv, const float* __restrict__ Wo,
        const int* __restrict__ msk,
        u16* __restrict__ xqb, u16* __restrict__ xkb, u16* __restrict__ xvb,
        u16* __restrict__ wqb, u16* __restrict__ wkb, u16* __restrict__ wvb,
        u16* __restrict__ wob, u64* __restrict__ prepM) {
    const int bid = blockIdx.x;
    const int tid = threadIdx.x;
    if (bid < 16384) {
        const float* in;
        u16* out;
        int i;
        if (bid < 12288) {
            const int z = bid >> 12;
            in = z == 0 ? xq : (z == 1 ? xk : xv);
            out = z == 0 ? xqb : (z == 1 ? xkb : xvb);
            i = (bid & 4095) * 256 + tid;
        } else {
            const int z = (bid - 12288) >> 10;
            in = z == 0 ? Wq : (z == 1 ? Wk : (z == 2 ? Wv : Wo));
            out = z == 0 ? wqb : (z == 1 ? wkb : (z == 2 ? wvb : wob));
            i = ((bid - 12288) & 1023) * 256 + tid;
        }
        const float4 v = ((const float4*)in)[i];
        ushort4 o;
        o.x = f2bf(v.x); o.y = f2bf(v.y); o.z = f2bf(v.z); o.w = f2bf(v.w);
        ((ushort4*)out)[i] = o;
    } else {
        const int wid = (bid - 16384) * 4 + (tid >> 6);  /* 0..8191 */
        const int lane = tid & 63;
        const int kt = wid & 31, qb = (wid >> 5) & 127, b = wid >> 12;
        const int q = qb * 16 + (lane & 15);
        const int kbase = kt * 64 + ((lane >> 4) << 2);
        const int* mrow = msk + ((size_t)b * kS + q) * kS;
        u64 keep = 0;
#pragma unroll
        for (int e = 0; e < 16; ++e) {
            const int k = kbase + (e >> 2) * 16 + (e & 3);
            const u64 bl = __ballot(mrow[k] != 0);
            if (lane == e) keep = bl;
        }
        if (lane < 16)
            prepM[(((size_t)b * 128 + qb) * 32 + kt) * 16 + lane] = keep;
    }
}

/* ---------------- bf16 GEMM: C = A[M,K] @ W[N,K]^T + bias ----------------
 * TILEM x 128 tile, BK=64, 4 waves, 16x16x32 MFMA, global_load_lds width-16,
 * XOR-swizzled LDS (rows 128B = 8 chunks; chunk c of row r at slot c^(r&7)).
 * TILEM=128: waves 2x2 of 64x64 (qkv).  TILEM=64: waves 2x2 of 32x64 (o_gemm,
 * doubles grid to 512 blocks = 2/CU instead of 1/CU).
 * MODE 0: bf16 out; MODE 2: f32 out; MODE 3: V^T out [(b*H+h)*64+d][s].
 */
template <int MODE, int TILEM>
__device__ __forceinline__ void gemm_bt_body(const u16* __restrict__ A,
                                             const u16* __restrict__ W,
                                             const float* __restrict__ bias,
                                             void* __restrict__ Cp) {
    constexpr int FM = TILEM / 32;           /* fm frags per wave: 4 or 2 */
    __shared__ u16 As[TILEM * 64];
    __shared__ u16 Bs[128 * 64];
    const int tid = threadIdx.x;
    const int wave = tid >> 6, lane = tid & 63;
    const int l15 = lane & 15, quad = lane >> 4, l7 = lane & 7;
    const int wr = wave >> 1, wc = wave & 1;
    const int m0 = (MODE == 3 ? blockIdx.x : blockIdx.y) * TILEM;
    const int n0 = (MODE == 3 ? blockIdx.y : blockIdx.x) * 128;

    const int srow = lane >> 3;          /* 0..7 */
    const int schk = l7 ^ srow;          /* global chunk this lane fetches */
    const u16* gA = A + (size_t)(m0 + (TILEM / 4) * wave + srow) * kD + schk * 8;
    const u16* gB = W + (size_t)(n0 + 32 * wave + srow) * kD + schk * 8;
    u16* lA = As + ((TILEM / 4) * wave) * 64;
    u16* lB = Bs + (32 * wave) * 64;

    f32x4 acc[FM][4];
#pragma unroll
    for (int i = 0; i < FM; ++i)
#pragma unroll
        for (int j = 0; j < 4; ++j) acc[i][j] = (f32x4)0.f;

    for (int kt = 0; kt < kD; kt += 64) {
        __syncthreads();
#pragma unroll
        for (int i = 0; i < TILEM / 32; ++i)
            async_copy16(gA + (size_t)(8 * i) * kD + kt, lA + (8 * i) * 64);
#pragma unroll
        for (int i = 0; i < 4; ++i)
            async_copy16(gB + (size_t)(8 * i) * kD + kt, lB + (8 * i) * 64);
        __syncthreads();

#pragma unroll
        for (int s = 0; s < 2; ++s) {
            const int rdoff = ((s * 4 + quad) ^ l7) * 8;
            s16x8 af[FM], bf[4];
#pragma unroll
            for (int fm = 0; fm < FM; ++fm)
                af[fm] = *(const s16x8*)(As + (wr * (TILEM / 2) + fm * 16 + l15) * 64 + rdoff);
#pragma unroll
            for (int fn = 0; fn < 4; ++fn)
                bf[fn] = *(const s16x8*)(Bs + (wc * 64 + fn * 16 + l15) * 64 + rdoff);
#pragma unroll
            for (int fm = 0; fm < FM; ++fm)
#pragma unroll
                for (int fn = 0; fn < 4; ++fn)
                    acc[fm][fn] = __builtin_amdgcn_mfma_f32_16x16x32_bf16(
                        af[fm], bf[fn], acc[fm][fn], 0, 0, 0);
        }
    }

    /* epilogue: C/D layout col=lane&15, row=quad*4+reg */
    if constexpr (MODE == 3) {
#pragma unroll
        for (int fn = 0; fn < 4; ++fn) {
            const int sglob = n0 + wc * 64 + fn * 16 + l15;
            const int bb = sglob >> 11, ss = sglob & (kS - 1);
#pragma unroll
            for (int fm = 0; fm < FM; ++fm) {
                const int dglob = m0 + wr * (TILEM / 2) + fm * 16 + quad * 4;
                const float4 b4 = *(const float4*)(bias + dglob);
                const float bb4[4] = {b4.x, b4.y, b4.z, b4.w};
                const int hh = dglob >> 6, dd = dglob & 63;
                u16* base = (u16*)Cp + ((size_t)(bb * kH + hh) * 64 + dd) * kS + ss;
#pragma unroll
                for (int r = 0; r < 4; ++r)
                    base[(size_t)r * kS] = f2bf(acc[fm][fn][r] + bb4[r]);
            }
        }
    } else {
#pragma unroll
        for (int fn = 0; fn < 4; ++fn) {
            const int col = n0 + wc * 64 + fn * 16 + l15;
            const float bv = bias[col];
#pragma unroll
            for (int fm = 0; fm < FM; ++fm) {
                const int row = m0 + wr * (TILEM / 2) + fm * 16 + quad * 4;
#pragma unroll
                for (int r = 0; r < 4; ++r) {
                    const float v = acc[fm][fn][r] + bv;
                    if constexpr (MODE == 0)
                        ((u16*)Cp)[(size_t)(row + r) * kD + col] = f2bf(v);
                    else
                        ((float*)Cp)[(size_t)(row + r) * kD + col] = v;
                }
            }
        }
    }
}

__global__ __launch_bounds__(256) void qkv_gemm(
        const u16* __restrict__ xq, const u16* __restrict__ xk, const u16* __restrict__ xv,
        const u16* __restrict__ wq, const u16* __restrict__ wk, const u16* __restrict__ wv,
        const float* __restrict__ bq, const float* __restrict__ bk, const float* __restrict__ bv,
        u16* __restrict__ q, u16* __restrict__ k, u16* __restrict__ vt) {
    const int z = blockIdx.z;
    if (z == 0)      gemm_bt_body<0, 128>(xq, wq, bq, q);
    else if (z == 1) gemm_bt_body<0, 128>(xk, wk, bk, k);
    else             gemm_bt_body<3, 128>(wv, xv, bv, vt);   /* V^T = Wv · X^T */
}

__global__ __launch_bounds__(256) void o_gemm(const u16* __restrict__ A,
                                              const u16* __restrict__ W,
                                              const float* __restrict__ bias,
                                              float* __restrict__ C) {
    gemm_bt_body<2, 64>(A, W, bias, C);
}

/* ---------------- MFMA flash attention (R4 verbatim) ----------------
 * Block = (64-query tile, b*h). Wave w owns queries [16w,16w+16).
 * Scores^T = K·Q^T; lane holds 16 scores of ONE query (col l15).
 * Fixed-max softmax: p = exp2(fma(s, kC, -8)) — no max pass, no alpha.
 * Mask applied via SGPR lane-mask v_cndmask (1 VALU/element).
 */
#define kC 0.180336880f   /* 0.125 * log2(e) */

__global__ __launch_bounds__(256) void attn_mfma(const u16* __restrict__ Qb,
                                                 const u16* __restrict__ Kb,
                                                 const u16* __restrict__ Vt,
                                                 const u64* __restrict__ prepM,
                                                 u16* __restrict__ Ob) {
    __shared__ u16 Qs[64 * 64];
    __shared__ u16 Ks[64 * 64];
    __shared__ u16 Vs[64 * 64];
    __shared__ u16 Ps[64 * 64];

    const int tid = threadIdx.x;
    const int wave = tid >> 6, lane = tid & 63;
    const int l15 = lane & 15, quad = lane >> 4, l7 = lane & 7;
    const int q0 = blockIdx.x * 64;
    const int b = blockIdx.y >> 4, h = blockIdx.y & 15;

    const int srow = lane >> 3;           /* 0..7 */
    const int schk = l7 ^ srow;

    /* stage Q once (natural [q][d]) */
    {
        const u16* g0 = Qb + ((size_t)(b * kS + q0 + 16 * wave + srow)) * kD + h * 64 + schk * 8;
        async_copy16(g0, Qs + (16 * wave) * 64);
        async_copy16(g0 + 8 * kD, Qs + (16 * wave + 8) * 64);
    }
    const u16* gK0 = Kb + ((size_t)(b * kS + 16 * wave + srow)) * kD + h * 64 + schk * 8;
    const u16* gV0 = Vt + ((size_t)((b * kH + h) * 64 + 16 * wave + srow)) * kS + schk * 8;

    /* wave-uniform mask base (scalar loads) */
    const int wave_u = __builtin_amdgcn_readfirstlane(wave);
    const u64* mbase = prepM + (((size_t)b * 128 + blockIdx.x * 4 + wave_u) * 32) * 16;

    f32x4 oacc[4];
#pragma unroll
    for (int i = 0; i < 4; ++i) oacc[i] = (f32x4)0.f;
    float l_r = 0.f;

    __syncthreads();   /* Q landed */
    s16x8 bq[2];
    bq[0] = *(const s16x8*)(Qs + (16 * wave + l15) * 64 + ((0 + quad) ^ l7) * 8);
    bq[1] = *(const s16x8*)(Qs + (16 * wave + l15) * 64 + ((4 + quad) ^ l7) * 8);
    u16* psrow = Ps + (16 * wave + l15) * 64;

    for (int kt = 0; kt < kS; kt += 64) {
        __syncthreads();                  /* prev K/V reads done */
        async_copy16(gK0 + (size_t)kt * kD, Ks + (16 * wave) * 64);
        async_copy16(gK0 + (size_t)(kt + 8) * kD, Ks + (16 * wave + 8) * 64);
        async_copy16(gV0 + kt, Vs + (16 * wave) * 64);
        async_copy16(gV0 + 8 * kS + kt, Vs + (16 * wave + 8) * 64);
        __syncthreads();                  /* staging landed */

        /* scores^T: D[key][query], A=K rows, B=Q rows */
        f32x4 s[4];
#pragma unroll
        for (int fn = 0; fn < 4; ++fn) s[fn] = (f32x4)0.f;
#pragma unroll
        for (int kc = 0; kc < 2; ++kc)
#pragma unroll
            for (int fn = 0; fn < 4; ++fn) {
                const s16x8 ak = *(const s16x8*)(Ks + (fn * 16 + l15) * 64 + ((kc * 4 + quad) ^ l7) * 8);
                s[fn] = __builtin_amdgcn_mfma_f32_16x16x32_bf16(ak, bq[kc], s[fn], 0, 0, 0);
            }

        /* fixed-max softmax + SGPR-mask zeroing */
        const u64* mt = mbase + (kt >> 6) * 16;
        float ps = 0.f;
#pragma unroll
        for (int fn = 0; fn < 4; ++fn)
#pragma unroll
            for (int r = 0; r < 4; ++r) {
                const u64 mm = mt[fn * 4 + r];
                const float p = exp2f(fmaf(s[fn][r], kC, -8.0f));
                float pm;
                asm("v_cndmask_b32 %0, 0, %1, %2" : "=v"(pm) : "v"(p), "s"(mm));
                s[fn][r] = pm;
                ps += pm;
            }
        ps += __shfl_xor(ps, 16);
        ps += __shfl_xor(ps, 32);
        l_r += ps;

        /* write P[q][k]: per fn one uint2 (4 keys) */
#pragma unroll
        for (int fn = 0; fn < 4; ++fn) {
            uint2 o;
            o.x = pack_bf2(s[fn][0], s[fn][1]);
            o.y = pack_bf2(s[fn][2], s[fn][3]);
            const int chunk = fn * 2 + (quad >> 1);
            *(uint2*)(psrow + ((chunk ^ l7) * 8) + (quad & 1) * 4) = o;
        }

        /* PV: O^T[d][q] += V^T[d][k] · P[q][k] (A=V^T, B=P, wave-private rows) */
#pragma unroll
        for (int kc = 0; kc < 2; ++kc) {
            const s16x8 bp = *(const s16x8*)(psrow + ((kc * 4 + quad) ^ l7) * 8);
#pragma unroll
            for (int fd = 0; fd < 4; ++fd) {
                const s16x8 av = *(const s16x8*)(Vs + (fd * 16 + l15) * 64 + ((kc * 4 + quad) ^ l7) * 8);
                oacc[fd] = __builtin_amdgcn_mfma_f32_16x16x32_bf16(av, bp, oacc[fd], 0, 0, 0);
            }
        }
    }

    /* epilogue: O^T[d][q] -> Ob[q][h*64+d] */
    const float inv = 1.f / l_r;
    const size_t orow = (size_t)(b * kS + q0 + 16 * wave + l15);
#pragma unroll
    for (int fd = 0; fd < 4; ++fd) {
        uint2 o;
        o.x = pack_bf2(oacc[fd][0] * inv, oacc[fd][1] * inv);
        o.y = pack_bf2(oacc[fd][2] * inv, oacc[fd][3] * inv);
        *(uint2*)(Ob + orow * kD + h * 64 + fd * 16 + quad * 4) = o;
    }
}

extern "C" void kernel_launch(void* const* d_in, const int* in_sizes, int n_in,
                              void* d_out, int out_size, void* d_ws, size_t ws_size,
                              hipStream_t stream) {
    const float* xq = (const float*)d_in[0];
    const float* xk = (const float*)d_in[1];
    const float* xv = (const float*)d_in[2];
    const int*  msk = (const int*)d_in[3];
    const float* Wq = (const float*)d_in[4];
    const float* bq = (const float*)d_in[5];
    const float* Wk = (const float*)d_in[6];
    const float* bk = (const float*)d_in[7];
    const float* Wv = (const float*)d_in[8];
    const float* bv = (const float*)d_in[9];
    const float* Wo = (const float*)d_in[10];
    const float* bo = (const float*)d_in[11];
    float* out = (float*)d_out;

    const size_t NX = (size_t)kM * kD;      /* 4,194,304 */
    const size_t NW = (size_t)kD * kD;      /* 1,048,576 */

    u64* prepM = (u64*)d_ws;                /* 1 MiB */
    u16* p = (u16*)((char*)d_ws + (1 << 20));
    u16* xqb = p; p += NX;
    u16* xkb = p; p += NX;
    u16* xvb = p; p += NX;
    u16* wqb = p; p += NW;
    u16* wkb = p; p += NW;
    u16* wvb = p; p += NW;
    u16* wob = p; p += NW;
    u16* qb  = p; p += NX;
    u16* kb  = p; p += NX;
    u16* vtb = p; p += NX;
    u16* ab  = xqb;                         /* reuse: xqb dead after qkv_gemm */

    prep<<<18432, 256, 0, stream>>>(xq, xk, xv, Wq, Wk, Wv, Wo, msk,
                                    xqb, xkb, xvb, wqb, wkb, wvb, wob, prepM);

    dim3 gq(kD / 128, kM / 128, 3);         /* (8,32,3) = 768 blocks */
    qkv_gemm<<<gq, 256, 0, stream>>>(xqb, xkb, xvb, wqb, wkb, wvb, bq, bk, bv, qb, kb, vtb);

    dim3 ga(kS / 64, kB * kH);              /* (32,32) = 1024 blocks */
    attn_mfma<<<ga, 256, 0, stream>>>(qb, kb, vtb, prepM, ab);

    dim3 go(kD / 128, kM / 64);             /* (8,64) = 512 blocks, 2/CU */
    o_gemm<<<go, 256, 0, stream>>>(ab, wob, bo, out);
}